// Round 1
// baseline (957.081 us; speedup 1.0000x reference)
//
#include <hip/hip_runtime.h>
#include <hip/hip_bf16.h>
#include <math.h>

#define Bsz 2
#define Cch 48
#define Hh 64
#define Ww 64
#define Nn 4096

// ---------------- K1 / K7 helper: conv1x1 over (B,C,N) layout ----------------
__global__ void k_conv1x1(const float* __restrict__ in, const float* __restrict__ Wt,
                          const float* __restrict__ bias, float* __restrict__ out,
                          int Cin, int Cout){
  int chunk = blockIdx.x & 15;            // N/256 = 16 chunks
  int o = (blockIdx.x >> 4) % Cout;
  int b = blockIdx.x / (16 * Cout);
  int p = chunk * 256 + threadIdx.x;
  float acc = bias[o];
  const float* ip = in + (b * Cin) * Nn + p;
  const float* wp = Wt + o * Cin;
  for (int c = 0; c < Cin; c++) acc += wp[c] * ip[c * Nn];
  out[(b * Cout + o) * Nn + p] = acc;
}

// ---------------- K2: dw3x3 + LN + GELU + pw(2) + tanh -> pos ----------------
__global__ void k_offset_pos(const float* __restrict__ q, const float* __restrict__ dww,
                             const float* __restrict__ dwb, const float* __restrict__ lng,
                             const float* __restrict__ lnb, const float* __restrict__ pww,
                             float* __restrict__ pos){
  int idx = blockIdx.x * 256 + threadIdx.x;
  if (idx >= Bsz * Nn) return;
  int b = idx >> 12;
  int p = idx & (Nn - 1);
  int y = p >> 6, x = p & 63;
  float t[Cch];
  float mean = 0.f;
  #pragma unroll
  for (int c = 0; c < Cch; c++){
    float acc = dwb[c];
    const float* qc = q + (b * Cch + c) * Nn;
    #pragma unroll
    for (int ky = -1; ky <= 1; ky++){
      int yy = y + ky;
      if (yy < 0 || yy >= Hh) continue;
      #pragma unroll
      for (int kx = -1; kx <= 1; kx++){
        int xx = x + kx;
        if (xx < 0 || xx >= Ww) continue;
        acc += qc[yy * Ww + xx] * dww[c * 9 + (ky + 1) * 3 + (kx + 1)];
      }
    }
    t[c] = acc; mean += acc;
  }
  mean *= (1.f / Cch);
  float var = 0.f;
  #pragma unroll
  for (int c = 0; c < Cch; c++){ float d = t[c] - mean; var += d * d; }
  var *= (1.f / Cch);
  float rstd = rsqrtf(var + 1e-5f);
  float o0 = 0.f, o1 = 0.f;
  #pragma unroll
  for (int c = 0; c < Cch; c++){
    float u = (t[c] - mean) * rstd * lng[c] + lnb[c];
    u = 0.5f * u * (1.f + erff(u * 0.70710678118654752f));   // exact gelu
    o0 += pww[c] * u;
    o1 += pww[Cch + c] * u;
  }
  float posy = tanhf(o0) * (2.f / 63.f) + ((0.5f + (float)y) * (2.f / 63.f) - 1.f);
  float posx = tanhf(o1) * (2.f / 63.f) + ((0.5f + (float)x) * (2.f / 63.f) - 1.f);
  pos[idx * 2 + 0] = posy;
  pos[idx * 2 + 1] = posx;
}

// ---------------- K3: bilinear grid sample of x at pos -> xs (B,n,C) --------
__global__ void k_sample(const float* __restrict__ x, const float* __restrict__ pos,
                         float* __restrict__ xs){
  int idx = blockIdx.x * 256 + threadIdx.x;
  if (idx >= Bsz * Nn) return;
  int b = idx >> 12;
  float py = pos[idx * 2], px = pos[idx * 2 + 1];
  float gx = (px + 1.f) * 0.5f * 63.f;
  float gy = (py + 1.f) * 0.5f * 63.f;
  float x0f = floorf(gx), y0f = floorf(gy);
  float wx = gx - x0f, wy = gy - y0f;
  int x0 = (int)x0f, y0 = (int)y0f, x1 = x0 + 1, y1 = y0 + 1;
  float w00 = (1.f - wy) * (1.f - wx), w01 = (1.f - wy) * wx;
  float w10 = wy * (1.f - wx),         w11 = wy * wx;
  bool vx0 = (x0 >= 0) && (x0 < Ww), vx1 = (x1 >= 0) && (x1 < Ww);
  bool vy0 = (y0 >= 0) && (y0 < Hh), vy1 = (y1 >= 0) && (y1 < Hh);
  if (!(vx0 && vy0)) w00 = 0.f;
  if (!(vx1 && vy0)) w01 = 0.f;
  if (!(vx0 && vy1)) w10 = 0.f;
  if (!(vx1 && vy1)) w11 = 0.f;
  int cx0 = min(max(x0, 0), Ww - 1), cx1 = min(max(x1, 0), Ww - 1);
  int cy0 = min(max(y0, 0), Hh - 1), cy1 = min(max(y1, 0), Hh - 1);
  int i00 = cy0 * Ww + cx0, i01 = cy0 * Ww + cx1;
  int i10 = cy1 * Ww + cx0, i11 = cy1 * Ww + cx1;
  const float* xb = x + (b * Cch) * Nn;
  float* op = xs + idx * Cch;
  #pragma unroll
  for (int c = 0; c < Cch; c++){
    const float* xc = xb + c * Nn;
    op[c] = w00 * xc[i00] + w01 * xc[i01] + w10 * xc[i10] + w11 * xc[i11];
  }
}

// ---------------- K4: k,v = W * xs + b, stored (B,n,C) -----------------------
__global__ void k_kv(const float* __restrict__ xs, const float* __restrict__ Wk,
                     const float* __restrict__ bk, const float* __restrict__ Wv,
                     const float* __restrict__ bv, float* __restrict__ kk,
                     float* __restrict__ vv){
  int idx = blockIdx.x * 256 + threadIdx.x;
  if (idx >= Bsz * Nn) return;
  float row[Cch];
  const float4* rp = (const float4*)(xs + idx * Cch);
  #pragma unroll
  for (int j = 0; j < Cch / 4; j++){
    float4 f = rp[j];
    row[j * 4 + 0] = f.x; row[j * 4 + 1] = f.y;
    row[j * 4 + 2] = f.z; row[j * 4 + 3] = f.w;
  }
  float* kp = kk + idx * Cch;
  float* vp = vv + idx * Cch;
  for (int o = 0; o < Cch; o++){
    float ak = bk[o], av = bv[o];
    const float* wkr = Wk + o * Cch;
    const float* wvr = Wv + o * Cch;
    #pragma unroll
    for (int c = 0; c < Cch; c++){ ak += wkr[c] * row[c]; av += wvr[c] * row[c]; }
    kp[o] = ak; vp[o] = av;
  }
}

// ---------------- K5: deformable attention, one block per (b,m) --------------
__global__ __launch_bounds__(256) void k_attn(const float* __restrict__ q,
                                              const float* __restrict__ kk,
                                              const float* __restrict__ vv,
                                              const float* __restrict__ pos,
                                              const float* __restrict__ rpe,
                                              float* __restrict__ out_dat){
  __shared__ __align__(16) float l_lds[Nn];
  __shared__ __align__(16) float qv[Cch];
  __shared__ float red[16];
  __shared__ float part[256];
  int tid = threadIdx.x;
  int b = blockIdx.x >> 12;
  int m = blockIdx.x & (Nn - 1);
  if (tid < Cch) qv[tid] = q[(b * Cch + tid) * Nn + m];
  __syncthreads();
  float qgy = (float)(m >> 6) * (2.f / 63.f) - 1.f;
  float qgx = (float)(m & 63) * (2.f / 63.f) - 1.f;
  const float scale = 0.14433756729740643f;   // 48^-0.5
  float lmax = -3.4e38f;
  const float4* q4 = (const float4*)qv;
  for (int i = 0; i < 16; i++){
    int nn = i * 256 + tid;
    const float4* kp = (const float4*)(kk + (b * Nn + nn) * Cch);
    float dot = 0.f;
    #pragma unroll
    for (int j = 0; j < Cch / 4; j++){
      float4 a = q4[j], kx = kp[j];
      dot += a.x * kx.x + a.y * kx.y + a.z * kx.z + a.w * kx.w;
    }
    float py = pos[(b * Nn + nn) * 2], px = pos[(b * Nn + nn) * 2 + 1];
    float dy = (qgy - py) * 0.5f, dx = (qgx - px) * 0.5f;
    float gxr = (dx + 1.f) * 95.f, gyr = (dy + 1.f) * 95.f;
    float x0f = floorf(gxr), y0f = floorf(gyr);
    float wx = gxr - x0f, wy = gyr - y0f;
    int x0 = (int)x0f, y0 = (int)y0f, x1 = x0 + 1, y1 = y0 + 1;
    float w00 = (1.f - wy) * (1.f - wx), w01 = (1.f - wy) * wx;
    float w10 = wy * (1.f - wx),         w11 = wy * wx;
    if (!((x0 >= 0) && (x0 < 191))) { w00 = 0.f; w10 = 0.f; }
    if (!((x1 >= 0) && (x1 < 191))) { w01 = 0.f; w11 = 0.f; }
    if (!((y0 >= 0) && (y0 < 191))) { w00 = 0.f; w01 = 0.f; }
    if (!((y1 >= 0) && (y1 < 191))) { w10 = 0.f; w11 = 0.f; }
    int cx0 = min(max(x0, 0), 190), cx1 = min(max(x1, 0), 190);
    int cy0 = min(max(y0, 0), 190), cy1 = min(max(y1, 0), 190);
    float bias = w00 * rpe[cy0 * 191 + cx0] + w01 * rpe[cy0 * 191 + cx1]
               + w10 * rpe[cy1 * 191 + cx0] + w11 * rpe[cy1 * 191 + cx1];
    float lg = dot * scale + bias;
    l_lds[nn] = lg;
    lmax = fmaxf(lmax, lg);
  }
  // block-reduce max
  float wm = lmax;
  #pragma unroll
  for (int o = 32; o; o >>= 1) wm = fmaxf(wm, __shfl_down(wm, o, 64));
  if ((tid & 63) == 0) red[tid >> 6] = wm;
  __syncthreads();
  if (tid == 0) red[8] = fmaxf(fmaxf(red[0], red[1]), fmaxf(red[2], red[3]));
  __syncthreads();
  float gmax = red[8];
  // exp + sum
  float lsum = 0.f;
  for (int i = 0; i < 16; i++){
    int nn = i * 256 + tid;
    float pe = expf(l_lds[nn] - gmax);
    l_lds[nn] = pe;
    lsum += pe;
  }
  float wsum = lsum;
  #pragma unroll
  for (int o = 32; o; o >>= 1) wsum += __shfl_down(wsum, o, 64);
  if ((tid & 63) == 0) red[4 + (tid >> 6)] = wsum;
  __syncthreads();
  if (tid == 0) red[9] = red[4] + red[5] + red[6] + red[7];
  __syncthreads();
  float rinv = 1.f / red[9];
  // phase C: out[c] = sum_n p[n] * v[n,c]
  int c = tid & 63, grp = tid >> 6;
  float acc = 0.f;
  if (c < Cch){
    const float* vb = vv + (b * Nn + grp * 1024) * Cch + c;
    const float* pl = l_lds + grp * 1024;
    for (int j = 0; j < 1024; j++) acc += pl[j] * vb[j * Cch];
  }
  part[tid] = acc;
  __syncthreads();
  if (tid < Cch)
    out_dat[(b * Cch + tid) * Nn + m] =
        (part[tid] + part[tid + 64] + part[tid + 128] + part[tid + 192]) * rinv;
}

// ---------------- K6: window attention (3 splits), 1 block/window ------------
__global__ __launch_bounds__(64) void k_win(const float* __restrict__ x,
                                            const float* __restrict__ iw,
                                            const float* __restrict__ ib,
                                            const float* __restrict__ bng,
                                            const float* __restrict__ bnb,
                                            const float* __restrict__ bnm,
                                            const float* __restrict__ bnv,
                                            float* __restrict__ wout){
  int s = blockIdx.x >> 7;        // split 0/1/2
  int r = blockIdx.x & 127;
  int b = r >> 6, wi = r & 63, t = threadIdx.x;
  int y, xp;
  if (s == 0){ y = (wi >> 3) * 8 + (t >> 3); xp = (wi & 7) * 8 + (t & 7); }
  else if (s == 1){ y = t; xp = wi; }      // column windows (dh=64,dw=1)
  else { y = wi; xp = t; }                  // row windows (dh=1,dw=64)
  int p = y * 64 + xp;
  __shared__ float qs[64 * 16];
  __shared__ float vs[64 * 16];
  float xrow[Cch];
  #pragma unroll
  for (int c = 0; c < Cch; c++) xrow[c] = x[(b * Cch + c) * Nn + p];
  float qrow[16];
  #pragma unroll
  for (int i = 0; i < 16; i++){
    int qc = s * 32 + i, vc = s * 32 + 16 + i;
    float aq = ib[qc], av = ib[vc];
    const float* wq_ = iw + qc * Cch;
    const float* wv_ = iw + vc * Cch;
    #pragma unroll
    for (int c = 0; c < Cch; c++){ aq += wq_[c] * xrow[c]; av += wv_[c] * xrow[c]; }
    aq = (aq - bnm[qc]) * rsqrtf(bnv[qc] + 1e-5f) * bng[qc] + bnb[qc];
    av = (av - bnm[vc]) * rsqrtf(bnv[vc] + 1e-5f) * bng[vc] + bnb[vc];
    qrow[i] = aq;
    qs[t * 16 + i] = aq;
    vs[t * 16 + i] = av;
  }
  __syncthreads();
  float l[64];
  float mx = -3.4e38f;
  #pragma unroll
  for (int j = 0; j < 64; j++){
    float d = 0.f;
    #pragma unroll
    for (int i = 0; i < 16; i++) d += qrow[i] * qs[j * 16 + i];  // qs[j..] broadcast
    l[j] = d;
    mx = fmaxf(mx, d);
  }
  float sum = 0.f;
  #pragma unroll
  for (int j = 0; j < 64; j++){ l[j] = expf(l[j] - mx); sum += l[j]; }
  float rinv = 1.f / sum;
  float o[16];
  #pragma unroll
  for (int i = 0; i < 16; i++) o[i] = 0.f;
  #pragma unroll
  for (int j = 0; j < 64; j++){
    float pj = l[j];
    #pragma unroll
    for (int i = 0; i < 16; i++) o[i] += pj * vs[j * 16 + i];
  }
  #pragma unroll
  for (int i = 0; i < 16; i++)
    wout[(b * Cch + s * 16 + i) * Nn + p] = o[i] * rinv;
}

// ---------------- K7: pout conv + 0.5/0.5 mix --------------------------------
__global__ void k_final(const float* __restrict__ win, const float* __restrict__ pw,
                        const float* __restrict__ pb, const float* __restrict__ od,
                        float* __restrict__ out){
  int chunk = blockIdx.x & 15;
  int o = (blockIdx.x >> 4) % Cch;
  int b = blockIdx.x / (16 * Cch);
  int p = chunk * 256 + threadIdx.x;
  float acc = pb[o];
  const float* ip = win + (b * Cch) * Nn + p;
  const float* wp = pw + o * Cch;
  #pragma unroll
  for (int c = 0; c < Cch; c++) acc += wp[c] * ip[c * Nn];
  out[(b * Cch + o) * Nn + p] = 0.5f * acc + 0.5f * od[(b * Cch + o) * Nn + p];
}

extern "C" void kernel_launch(void* const* d_in, const int* in_sizes, int n_in,
                              void* d_out, int out_size, void* d_ws, size_t ws_size,
                              hipStream_t stream){
  const float* x   = (const float*)d_in[0];
  const float* Wq  = (const float*)d_in[1];
  const float* bq  = (const float*)d_in[2];
  const float* dww = (const float*)d_in[3];
  const float* dwb = (const float*)d_in[4];
  const float* lng = (const float*)d_in[5];
  const float* lnb = (const float*)d_in[6];
  const float* pww = (const float*)d_in[7];
  const float* Wk  = (const float*)d_in[8];
  const float* bk  = (const float*)d_in[9];
  const float* Wv  = (const float*)d_in[10];
  const float* bv  = (const float*)d_in[11];
  const float* iw  = (const float*)d_in[12];
  const float* ib  = (const float*)d_in[13];
  const float* bng = (const float*)d_in[14];
  const float* bnb = (const float*)d_in[15];
  const float* bnm = (const float*)d_in[16];
  const float* bnv = (const float*)d_in[17];
  const float* pw  = (const float*)d_in[18];
  const float* pb  = (const float*)d_in[19];
  const float* rpe = (const float*)d_in[20];

  float* ws   = (float*)d_ws;
  float* q    = ws;                  // 393216
  float* pos  = ws + 393216;         // 16384
  float* xs   = ws + 409600;         // 393216
  float* kk   = ws + 802816;         // 393216
  float* vv   = ws + 1196032;        // 393216
  float* wout = ws + 1589248;        // 393216
  float* od   = ws + 1982464;        // 393216
  float* out  = (float*)d_out;

  k_conv1x1  <<<Bsz * Cch * 16, 256, 0, stream>>>(x, Wq, bq, q, Cch, Cch);
  k_offset_pos<<<(Bsz * Nn) / 256, 256, 0, stream>>>(q, dww, dwb, lng, lnb, pww, pos);
  k_sample   <<<(Bsz * Nn) / 256, 256, 0, stream>>>(x, pos, xs);
  k_kv       <<<(Bsz * Nn) / 256, 256, 0, stream>>>(xs, Wk, bk, Wv, bv, kk, vv);
  k_attn     <<<Bsz * Nn, 256, 0, stream>>>(q, kk, vv, pos, rpe, od);
  k_win      <<<384, 64, 0, stream>>>(x, iw, ib, bng, bnb, bnm, bnv, wout);
  k_final    <<<Bsz * Cch * 16, 256, 0, stream>>>(wout, pw, pb, od, out);
}

// Round 2
// 565.360 us; speedup vs baseline: 1.6929x; 1.6929x over previous
//
#include <hip/hip_runtime.h>
#include <hip/hip_bf16.h>
#include <math.h>

#define Bsz 2
#define Cch 48
#define Hh 64
#define Ww 64
#define Nn 4096

// ---------------- K1 / K7 helper: conv1x1 over (B,C,N) layout ----------------
__global__ void k_conv1x1(const float* __restrict__ in, const float* __restrict__ Wt,
                          const float* __restrict__ bias, float* __restrict__ out,
                          int Cin, int Cout){
  int chunk = blockIdx.x & 15;            // N/256 = 16 chunks
  int o = (blockIdx.x >> 4) % Cout;
  int b = blockIdx.x / (16 * Cout);
  int p = chunk * 256 + threadIdx.x;
  float acc = bias[o];
  const float* ip = in + (b * Cin) * Nn + p;
  const float* wp = Wt + o * Cin;
  for (int c = 0; c < Cin; c++) acc += wp[c] * ip[c * Nn];
  out[(b * Cout + o) * Nn + p] = acc;
}

// ---------------- K2: dw3x3 + LN + GELU + pw(2) + tanh -> pos ----------------
__global__ void k_offset_pos(const float* __restrict__ q, const float* __restrict__ dww,
                             const float* __restrict__ dwb, const float* __restrict__ lng,
                             const float* __restrict__ lnb, const float* __restrict__ pww,
                             float* __restrict__ pos){
  int idx = blockIdx.x * 256 + threadIdx.x;
  if (idx >= Bsz * Nn) return;
  int b = idx >> 12;
  int p = idx & (Nn - 1);
  int y = p >> 6, x = p & 63;
  float t[Cch];
  float mean = 0.f;
  #pragma unroll
  for (int c = 0; c < Cch; c++){
    float acc = dwb[c];
    const float* qc = q + (b * Cch + c) * Nn;
    #pragma unroll
    for (int ky = -1; ky <= 1; ky++){
      int yy = y + ky;
      if (yy < 0 || yy >= Hh) continue;
      #pragma unroll
      for (int kx = -1; kx <= 1; kx++){
        int xx = x + kx;
        if (xx < 0 || xx >= Ww) continue;
        acc += qc[yy * Ww + xx] * dww[c * 9 + (ky + 1) * 3 + (kx + 1)];
      }
    }
    t[c] = acc; mean += acc;
  }
  mean *= (1.f / Cch);
  float var = 0.f;
  #pragma unroll
  for (int c = 0; c < Cch; c++){ float d = t[c] - mean; var += d * d; }
  var *= (1.f / Cch);
  float rstd = rsqrtf(var + 1e-5f);
  float o0 = 0.f, o1 = 0.f;
  #pragma unroll
  for (int c = 0; c < Cch; c++){
    float u = (t[c] - mean) * rstd * lng[c] + lnb[c];
    u = 0.5f * u * (1.f + erff(u * 0.70710678118654752f));   // exact gelu
    o0 += pww[c] * u;
    o1 += pww[Cch + c] * u;
  }
  float posy = tanhf(o0) * (2.f / 63.f) + ((0.5f + (float)y) * (2.f / 63.f) - 1.f);
  float posx = tanhf(o1) * (2.f / 63.f) + ((0.5f + (float)x) * (2.f / 63.f) - 1.f);
  pos[idx * 2 + 0] = posy;
  pos[idx * 2 + 1] = posx;
}

// ---------------- K3: bilinear grid sample of x at pos -> xs (B,n,C) --------
__global__ void k_sample(const float* __restrict__ x, const float* __restrict__ pos,
                         float* __restrict__ xs){
  int idx = blockIdx.x * 256 + threadIdx.x;
  if (idx >= Bsz * Nn) return;
  int b = idx >> 12;
  float py = pos[idx * 2], px = pos[idx * 2 + 1];
  float gx = (px + 1.f) * 0.5f * 63.f;
  float gy = (py + 1.f) * 0.5f * 63.f;
  float x0f = floorf(gx), y0f = floorf(gy);
  float wx = gx - x0f, wy = gy - y0f;
  int x0 = (int)x0f, y0 = (int)y0f, x1 = x0 + 1, y1 = y0 + 1;
  float w00 = (1.f - wy) * (1.f - wx), w01 = (1.f - wy) * wx;
  float w10 = wy * (1.f - wx),         w11 = wy * wx;
  bool vx0 = (x0 >= 0) && (x0 < Ww), vx1 = (x1 >= 0) && (x1 < Ww);
  bool vy0 = (y0 >= 0) && (y0 < Hh), vy1 = (y1 >= 0) && (y1 < Hh);
  if (!(vx0 && vy0)) w00 = 0.f;
  if (!(vx1 && vy0)) w01 = 0.f;
  if (!(vx0 && vy1)) w10 = 0.f;
  if (!(vx1 && vy1)) w11 = 0.f;
  int cx0 = min(max(x0, 0), Ww - 1), cx1 = min(max(x1, 0), Ww - 1);
  int cy0 = min(max(y0, 0), Hh - 1), cy1 = min(max(y1, 0), Hh - 1);
  int i00 = cy0 * Ww + cx0, i01 = cy0 * Ww + cx1;
  int i10 = cy1 * Ww + cx0, i11 = cy1 * Ww + cx1;
  const float* xb = x + (b * Cch) * Nn;
  float* op = xs + idx * Cch;
  #pragma unroll
  for (int c = 0; c < Cch; c++){
    const float* xc = xb + c * Nn;
    op[c] = w00 * xc[i00] + w01 * xc[i01] + w10 * xc[i10] + w11 * xc[i11];
  }
}

// ---------------- K4: k,v = W * xs + b, stored (B,n,C) -----------------------
__global__ void k_kv(const float* __restrict__ xs, const float* __restrict__ Wk,
                     const float* __restrict__ bk, const float* __restrict__ Wv,
                     const float* __restrict__ bv, float* __restrict__ kk,
                     float* __restrict__ vv){
  int idx = blockIdx.x * 256 + threadIdx.x;
  if (idx >= Bsz * Nn) return;
  float row[Cch];
  const float4* rp = (const float4*)(xs + idx * Cch);
  #pragma unroll
  for (int j = 0; j < Cch / 4; j++){
    float4 f = rp[j];
    row[j * 4 + 0] = f.x; row[j * 4 + 1] = f.y;
    row[j * 4 + 2] = f.z; row[j * 4 + 3] = f.w;
  }
  float* kp = kk + idx * Cch;
  float* vp = vv + idx * Cch;
  for (int o = 0; o < Cch; o++){
    float ak = bk[o], av = bv[o];
    const float* wkr = Wk + o * Cch;
    const float* wvr = Wv + o * Cch;
    #pragma unroll
    for (int c = 0; c < Cch; c++){ ak += wkr[c] * row[c]; av += wvr[c] * row[c]; }
    kp[o] = ak; vp[o] = av;
  }
}

// ---------------- K5: flash-style tiled deformable attention -----------------
// TM=16 queries/block (all same image row -> RPE y-side is per-n only),
// TN=128 key chunk in LDS. 256 threads: mq = tid>>4 (query), sub = tid&15.
__global__ __launch_bounds__(256, 2) void k_attn(const float* __restrict__ q,
                                                 const float* __restrict__ kk,
                                                 const float* __restrict__ vv,
                                                 const float* __restrict__ pos,
                                                 const float* __restrict__ rpe,
                                                 float* __restrict__ out_dat){
  __shared__ __align__(16) float ks[128][52];   // pad 48->52: <=2-way conflicts
  __shared__ __align__(16) float vs[128][52];
  __shared__ __align__(16) float ps[16][132];   // logits/probs tile
  __shared__ float axs[128], wy0s[128], wy1s[128];
  __shared__ int r0s[128], r1s[128];

  const int tid = threadIdx.x;
  const int b = blockIdx.x >> 8;
  const int m0 = (blockIdx.x & 255) * 16;
  const int mq = tid >> 4, sub = tid & 15;
  const int m = m0 + mq;

  // q row for this thread's query -> registers (reused all chunks)
  float qreg[48];
  #pragma unroll
  for (int k = 0; k < 48; k++) qreg[k] = q[(b * 48 + k) * Nn + m];

  const float qgx = (float)(m & 63) * (2.f / 63.f) - 1.f;
  const float bx = 47.5f * qgx;
  const float qgy = (float)(m0 >> 6) * (2.f / 63.f) - 1.f;  // same row for all 16 m
  const float cybase = 95.f + 47.5f * qgy;
  const float scale = 0.14433756729740643f;   // 48^-0.5

  float acc0 = 0.f, acc1 = 0.f, acc2 = 0.f, acc3 = 0.f;
  float m_run = -3.4e38f, s_run = 0.f;
  const int c0 = sub * 4;     // channels (only sub<12 active in AV)

  for (int ch = 0; ch < 32; ch++){
    const int n0 = ch * 128;
    // ---- stage k/v tiles (coalesced float4, 6 each per thread) ----
    const float4* kg = (const float4*)(kk + (size_t)(b * Nn + n0) * 48);
    const float4* vg = (const float4*)(vv + (size_t)(b * Nn + n0) * 48);
    #pragma unroll
    for (int j = 0; j < 6; j++){
      int f = tid + j * 256;
      int r = f / 12, c4 = (f % 12) * 4;
      *(float4*)&ks[r][c4] = kg[f];
      *(float4*)&vs[r][c4] = vg[f];
    }
    // ---- per-n bias precompute (y-side + ax) ----
    if (tid < 128){
      int n = tid;
      float py = pos[(b * Nn + n0 + n) * 2];
      float px = pos[(b * Nn + n0 + n) * 2 + 1];
      float gyr = cybase - 47.5f * py;
      float y0f = floorf(gyr);
      float wy = gyr - y0f;
      int y0 = (int)y0f, y1 = y0 + 1;
      wy0s[n] = (y0 >= 0 && y0 < 191) ? (1.f - wy) : 0.f;
      wy1s[n] = (y1 >= 0 && y1 < 191) ? wy : 0.f;
      r0s[n] = min(max(y0, 0), 190) * 191;
      r1s[n] = min(max(y1, 0), 190) * 191;
      axs[n] = 95.f - 47.5f * px;
    }
    __syncthreads();
    // ---- logits: each thread 8 dots (its mq, n = sub+16j) ----
    #pragma unroll
    for (int j = 0; j < 8; j++){
      int n = sub + 16 * j;
      float dot = 0.f;
      #pragma unroll
      for (int k4 = 0; k4 < 12; k4++){
        float4 kv = *(const float4*)&ks[n][k4 * 4];
        dot = fmaf(qreg[4 * k4 + 0], kv.x, dot);
        dot = fmaf(qreg[4 * k4 + 1], kv.y, dot);
        dot = fmaf(qreg[4 * k4 + 2], kv.z, dot);
        dot = fmaf(qreg[4 * k4 + 3], kv.w, dot);
      }
      float gxr = axs[n] + bx;
      float x0f = floorf(gxr);
      float wx = gxr - x0f;
      int x0 = (int)x0f, x1 = x0 + 1;
      float wx0 = (x0 >= 0 && x0 < 191) ? (1.f - wx) : 0.f;
      float wx1 = (x1 >= 0 && x1 < 191) ? wx : 0.f;
      int cx0 = min(max(x0, 0), 190), cx1 = min(max(x1, 0), 190);
      int r0 = r0s[n], r1 = r1s[n];
      float bias = wy0s[n] * (wx0 * rpe[r0 + cx0] + wx1 * rpe[r0 + cx1])
                 + wy1s[n] * (wx0 * rpe[r1 + cx0] + wx1 * rpe[r1 + cx1]);
      ps[mq][n] = fmaf(dot, scale, bias);
    }
    // ps row is touched only by this wave's 16-lane group -> no barrier needed.
    // ---- online softmax over this chunk ----
    float4 la = *(const float4*)&ps[mq][sub * 8];
    float4 lb = *(const float4*)&ps[mq][sub * 8 + 4];
    float lm = fmaxf(fmaxf(fmaxf(la.x, la.y), fmaxf(la.z, la.w)),
                     fmaxf(fmaxf(lb.x, lb.y), fmaxf(lb.z, lb.w)));
    #pragma unroll
    for (int msk = 1; msk < 16; msk <<= 1) lm = fmaxf(lm, __shfl_xor(lm, msk));
    float mnew = fmaxf(m_run, lm);
    float alpha = __expf(m_run - mnew);
    la.x = __expf(la.x - mnew); la.y = __expf(la.y - mnew);
    la.z = __expf(la.z - mnew); la.w = __expf(la.w - mnew);
    lb.x = __expf(lb.x - mnew); lb.y = __expf(lb.y - mnew);
    lb.z = __expf(lb.z - mnew); lb.w = __expf(lb.w - mnew);
    float lsum = la.x + la.y + la.z + la.w + lb.x + lb.y + lb.z + lb.w;
    *(float4*)&ps[mq][sub * 8] = la;
    *(float4*)&ps[mq][sub * 8 + 4] = lb;
    #pragma unroll
    for (int msk = 1; msk < 16; msk <<= 1) lsum += __shfl_xor(lsum, msk);
    s_run = fmaf(s_run, alpha, lsum);
    m_run = mnew;
    acc0 *= alpha; acc1 *= alpha; acc2 *= alpha; acc3 *= alpha;
    // ---- AV accumulate: sub<12 own 4 channels (float4 of v) ----
    if (sub < 12){
      #pragma unroll 8
      for (int n4 = 0; n4 < 128; n4 += 4){
        float4 p4 = *(const float4*)&ps[mq][n4];
        float4 va = *(const float4*)&vs[n4 + 0][c0];
        float4 vb = *(const float4*)&vs[n4 + 1][c0];
        float4 vc = *(const float4*)&vs[n4 + 2][c0];
        float4 vd = *(const float4*)&vs[n4 + 3][c0];
        acc0 = fmaf(p4.x, va.x, acc0); acc1 = fmaf(p4.x, va.y, acc1);
        acc2 = fmaf(p4.x, va.z, acc2); acc3 = fmaf(p4.x, va.w, acc3);
        acc0 = fmaf(p4.y, vb.x, acc0); acc1 = fmaf(p4.y, vb.y, acc1);
        acc2 = fmaf(p4.y, vb.z, acc2); acc3 = fmaf(p4.y, vb.w, acc3);
        acc0 = fmaf(p4.z, vc.x, acc0); acc1 = fmaf(p4.z, vc.y, acc1);
        acc2 = fmaf(p4.z, vc.z, acc2); acc3 = fmaf(p4.z, vc.w, acc3);
        acc0 = fmaf(p4.w, vd.x, acc0); acc1 = fmaf(p4.w, vd.y, acc1);
        acc2 = fmaf(p4.w, vd.z, acc2); acc3 = fmaf(p4.w, vd.w, acc3);
      }
    }
    __syncthreads();   // protect ks/vs/bias arrays for next chunk's staging
  }
  float rinv = 1.f / s_run;
  if (sub < 12){
    out_dat[(b * 48 + c0 + 0) * Nn + m] = acc0 * rinv;
    out_dat[(b * 48 + c0 + 1) * Nn + m] = acc1 * rinv;
    out_dat[(b * 48 + c0 + 2) * Nn + m] = acc2 * rinv;
    out_dat[(b * 48 + c0 + 3) * Nn + m] = acc3 * rinv;
  }
}

// ---------------- K6: window attention (3 splits), 1 block/window ------------
__global__ __launch_bounds__(64) void k_win(const float* __restrict__ x,
                                            const float* __restrict__ iw,
                                            const float* __restrict__ ib,
                                            const float* __restrict__ bng,
                                            const float* __restrict__ bnb,
                                            const float* __restrict__ bnm,
                                            const float* __restrict__ bnv,
                                            float* __restrict__ wout){
  int s = blockIdx.x >> 7;        // split 0/1/2
  int r = blockIdx.x & 127;
  int b = r >> 6, wi = r & 63, t = threadIdx.x;
  int y, xp;
  if (s == 0){ y = (wi >> 3) * 8 + (t >> 3); xp = (wi & 7) * 8 + (t & 7); }
  else if (s == 1){ y = t; xp = wi; }      // column windows (dh=64,dw=1)
  else { y = wi; xp = t; }                  // row windows (dh=1,dw=64)
  int p = y * 64 + xp;
  __shared__ float qs[64 * 16];
  __shared__ float vs[64 * 16];
  float xrow[Cch];
  #pragma unroll
  for (int c = 0; c < Cch; c++) xrow[c] = x[(b * Cch + c) * Nn + p];
  float qrow[16];
  #pragma unroll
  for (int i = 0; i < 16; i++){
    int qc = s * 32 + i, vc = s * 32 + 16 + i;
    float aq = ib[qc], av = ib[vc];
    const float* wq_ = iw + qc * Cch;
    const float* wv_ = iw + vc * Cch;
    #pragma unroll
    for (int c = 0; c < Cch; c++){ aq += wq_[c] * xrow[c]; av += wv_[c] * xrow[c]; }
    aq = (aq - bnm[qc]) * rsqrtf(bnv[qc] + 1e-5f) * bng[qc] + bnb[qc];
    av = (av - bnm[vc]) * rsqrtf(bnv[vc] + 1e-5f) * bng[vc] + bnb[vc];
    qrow[i] = aq;
    qs[t * 16 + i] = aq;
    vs[t * 16 + i] = av;
  }
  __syncthreads();
  float l[64];
  float mx = -3.4e38f;
  #pragma unroll
  for (int j = 0; j < 64; j++){
    float d = 0.f;
    #pragma unroll
    for (int i = 0; i < 16; i++) d += qrow[i] * qs[j * 16 + i];
    l[j] = d;
    mx = fmaxf(mx, d);
  }
  float sum = 0.f;
  #pragma unroll
  for (int j = 0; j < 64; j++){ l[j] = expf(l[j] - mx); sum += l[j]; }
  float rinv = 1.f / sum;
  float o[16];
  #pragma unroll
  for (int i = 0; i < 16; i++) o[i] = 0.f;
  #pragma unroll
  for (int j = 0; j < 64; j++){
    float pj = l[j];
    #pragma unroll
    for (int i = 0; i < 16; i++) o[i] += pj * vs[j * 16 + i];
  }
  #pragma unroll
  for (int i = 0; i < 16; i++)
    wout[(b * Cch + s * 16 + i) * Nn + p] = o[i] * rinv;
}

// ---------------- K7: pout conv + 0.5/0.5 mix --------------------------------
__global__ void k_final(const float* __restrict__ win, const float* __restrict__ pw,
                        const float* __restrict__ pb, const float* __restrict__ od,
                        float* __restrict__ out){
  int chunk = blockIdx.x & 15;
  int o = (blockIdx.x >> 4) % Cch;
  int b = blockIdx.x / (16 * Cch);
  int p = chunk * 256 + threadIdx.x;
  float acc = pb[o];
  const float* ip = win + (b * Cch) * Nn + p;
  const float* wp = pw + o * Cch;
  #pragma unroll
  for (int c = 0; c < Cch; c++) acc += wp[c] * ip[c * Nn];
  out[(b * Cch + o) * Nn + p] = 0.5f * acc + 0.5f * od[(b * Cch + o) * Nn + p];
}

extern "C" void kernel_launch(void* const* d_in, const int* in_sizes, int n_in,
                              void* d_out, int out_size, void* d_ws, size_t ws_size,
                              hipStream_t stream){
  const float* x   = (const float*)d_in[0];
  const float* Wq  = (const float*)d_in[1];
  const float* bq  = (const float*)d_in[2];
  const float* dww = (const float*)d_in[3];
  const float* dwb = (const float*)d_in[4];
  const float* lng = (const float*)d_in[5];
  const float* lnb = (const float*)d_in[6];
  const float* pww = (const float*)d_in[7];
  const float* Wk  = (const float*)d_in[8];
  const float* bk  = (const float*)d_in[9];
  const float* Wv  = (const float*)d_in[10];
  const float* bv  = (const float*)d_in[11];
  const float* iw  = (const float*)d_in[12];
  const float* ib  = (const float*)d_in[13];
  const float* bng = (const float*)d_in[14];
  const float* bnb = (const float*)d_in[15];
  const float* bnm = (const float*)d_in[16];
  const float* bnv = (const float*)d_in[17];
  const float* pw  = (const float*)d_in[18];
  const float* pb  = (const float*)d_in[19];
  const float* rpe = (const float*)d_in[20];

  float* ws   = (float*)d_ws;
  float* q    = ws;                  // 393216
  float* pos  = ws + 393216;         // 16384
  float* xs   = ws + 409600;         // 393216
  float* kk   = ws + 802816;         // 393216
  float* vv   = ws + 1196032;        // 393216
  float* wout = ws + 1589248;        // 393216
  float* od   = ws + 1982464;        // 393216
  float* out  = (float*)d_out;

  k_conv1x1  <<<Bsz * Cch * 16, 256, 0, stream>>>(x, Wq, bq, q, Cch, Cch);
  k_offset_pos<<<(Bsz * Nn) / 256, 256, 0, stream>>>(q, dww, dwb, lng, lnb, pww, pos);
  k_sample   <<<(Bsz * Nn) / 256, 256, 0, stream>>>(x, pos, xs);
  k_kv       <<<(Bsz * Nn) / 256, 256, 0, stream>>>(xs, Wk, bk, Wv, bv, kk, vv);
  k_attn     <<<Bsz * 256, 256, 0, stream>>>(q, kk, vv, pos, rpe, od);
  k_win      <<<384, 64, 0, stream>>>(x, iw, ib, bng, bnb, bnm, bnv, wout);
  k_final    <<<Bsz * Cch * 16, 256, 0, stream>>>(wout, pw, pb, od, out);
}

// Round 5
// 509.493 us; speedup vs baseline: 1.8785x; 1.1097x over previous
//
#include <hip/hip_runtime.h>
#include <hip/hip_bf16.h>
#include <math.h>

#define Bsz 2
#define Cch 48
#define Hh 64
#define Ww 64
#define Nn 4096

typedef __bf16 bf16;
typedef __attribute__((ext_vector_type(8))) __bf16 bf16x8;
typedef __attribute__((ext_vector_type(4))) float f32x4;

// ---------------- K1: conv1x1 -> q (B,C,N) fp32 + q_bf (B,m,64) bf16 --------
__global__ void k_conv1x1(const float* __restrict__ in, const float* __restrict__ Wt,
                          const float* __restrict__ bias, float* __restrict__ out,
                          bf16* __restrict__ qbf){
  int chunk = blockIdx.x & 15;            // N/256 = 16 chunks
  int o = (blockIdx.x >> 4) % Cch;
  int b = blockIdx.x / (16 * Cch);
  int p = chunk * 256 + threadIdx.x;
  float acc = bias[o];
  const float* ip = in + (b * Cch) * Nn + p;
  const float* wp = Wt + o * Cch;
  #pragma unroll
  for (int c = 0; c < Cch; c++) acc += wp[c] * ip[c * Nn];
  out[(b * Cch + o) * Nn + p] = acc;
  size_t qb = ((size_t)(b * Nn + p)) * 64;
  qbf[qb + o] = (bf16)acc;
  if (o < 16) qbf[qb + 48 + o] = (bf16)0.f;   // zero-pad k=48..63
}

// ---------------- K2: dw3x3 + LN + GELU + pw(2) + tanh -> pos ----------------
__global__ void k_offset_pos(const float* __restrict__ q, const float* __restrict__ dww,
                             const float* __restrict__ dwb, const float* __restrict__ lng,
                             const float* __restrict__ lnb, const float* __restrict__ pww,
                             float* __restrict__ pos){
  int idx = blockIdx.x * 64 + threadIdx.x;
  if (idx >= Bsz * Nn) return;
  int b = idx >> 12;
  int p = idx & (Nn - 1);
  int y = p >> 6, x = p & 63;
  float t[Cch];
  float mean = 0.f;
  #pragma unroll
  for (int c = 0; c < Cch; c++){
    float acc = dwb[c];
    const float* qc = q + (b * Cch + c) * Nn;
    #pragma unroll
    for (int ky = -1; ky <= 1; ky++){
      int yy = y + ky;
      if (yy < 0 || yy >= Hh) continue;
      #pragma unroll
      for (int kx = -1; kx <= 1; kx++){
        int xx = x + kx;
        if (xx < 0 || xx >= Ww) continue;
        acc += qc[yy * Ww + xx] * dww[c * 9 + (ky + 1) * 3 + (kx + 1)];
      }
    }
    t[c] = acc; mean += acc;
  }
  mean *= (1.f / Cch);
  float var = 0.f;
  #pragma unroll
  for (int c = 0; c < Cch; c++){ float d = t[c] - mean; var += d * d; }
  var *= (1.f / Cch);
  float rstd = rsqrtf(var + 1e-5f);
  float o0 = 0.f, o1 = 0.f;
  #pragma unroll
  for (int c = 0; c < Cch; c++){
    float u = (t[c] - mean) * rstd * lng[c] + lnb[c];
    u = 0.5f * u * (1.f + erff(u * 0.70710678118654752f));   // exact gelu
    o0 += pww[c] * u;
    o1 += pww[Cch + c] * u;
  }
  float posy = tanhf(o0) * (2.f / 63.f) + ((0.5f + (float)y) * (2.f / 63.f) - 1.f);
  float posx = tanhf(o1) * (2.f / 63.f) + ((0.5f + (float)x) * (2.f / 63.f) - 1.f);
  pos[idx * 2 + 0] = posy;
  pos[idx * 2 + 1] = posx;
}

// ---------------- K3: bilinear grid sample of x at pos -> xs (B,n,C) --------
__global__ void k_sample(const float* __restrict__ x, const float* __restrict__ pos,
                         float* __restrict__ xs){
  int idx = blockIdx.x * 64 + threadIdx.x;
  if (idx >= Bsz * Nn) return;
  int b = idx >> 12;
  float py = pos[idx * 2], px = pos[idx * 2 + 1];
  float gx = (px + 1.f) * 0.5f * 63.f;
  float gy = (py + 1.f) * 0.5f * 63.f;
  float x0f = floorf(gx), y0f = floorf(gy);
  float wx = gx - x0f, wy = gy - y0f;
  int x0 = (int)x0f, y0 = (int)y0f, x1 = x0 + 1, y1 = y0 + 1;
  float w00 = (1.f - wy) * (1.f - wx), w01 = (1.f - wy) * wx;
  float w10 = wy * (1.f - wx),         w11 = wy * wx;
  bool vx0 = (x0 >= 0) && (x0 < Ww), vx1 = (x1 >= 0) && (x1 < Ww);
  bool vy0 = (y0 >= 0) && (y0 < Hh), vy1 = (y1 >= 0) && (y1 < Hh);
  if (!(vx0 && vy0)) w00 = 0.f;
  if (!(vx1 && vy0)) w01 = 0.f;
  if (!(vx0 && vy1)) w10 = 0.f;
  if (!(vx1 && vy1)) w11 = 0.f;
  int cx0 = min(max(x0, 0), Ww - 1), cx1 = min(max(x1, 0), Ww - 1);
  int cy0 = min(max(y0, 0), Hh - 1), cy1 = min(max(y1, 0), Hh - 1);
  int i00 = cy0 * Ww + cx0, i01 = cy0 * Ww + cx1;
  int i10 = cy1 * Ww + cx0, i11 = cy1 * Ww + cx1;
  const float* xb = x + (b * Cch) * Nn;
  float* op = xs + idx * Cch;
  #pragma unroll
  for (int c = 0; c < Cch; c++){
    const float* xc = xb + c * Nn;
    op[c] = w00 * xc[i00] + w01 * xc[i01] + w10 * xc[i10] + w11 * xc[i11];
  }
}

// ---------------- K4: k,v = W * xs + b -> kk_bf [n][64] bf16, vt_bf (B,C,N) --
__global__ void k_kv(const float* __restrict__ xs, const float* __restrict__ Wk,
                     const float* __restrict__ bk, const float* __restrict__ Wv,
                     const float* __restrict__ bv, bf16* __restrict__ kk_bf,
                     bf16* __restrict__ vt_bf){
  int idx = blockIdx.x * 64 + threadIdx.x;
  if (idx >= Bsz * Nn) return;
  int b = idx >> 12;
  int n = idx & (Nn - 1);
  float row[Cch];
  const float4* rp = (const float4*)(xs + (size_t)idx * Cch);
  #pragma unroll
  for (int j = 0; j < Cch / 4; j++){
    float4 f = rp[j];
    row[j * 4 + 0] = f.x; row[j * 4 + 1] = f.y;
    row[j * 4 + 2] = f.z; row[j * 4 + 3] = f.w;
  }
  __align__(16) bf16 krow[64];
  #pragma unroll
  for (int j = 48; j < 64; j++) krow[j] = (bf16)0.f;
  for (int o = 0; o < Cch; o++){
    float ak = bk[o], av = bv[o];
    const float* wkr = Wk + o * Cch;
    const float* wvr = Wv + o * Cch;
    #pragma unroll
    for (int c = 0; c < Cch; c++){ ak += wkr[c] * row[c]; av += wvr[c] * row[c]; }
    krow[o] = (bf16)ak;
    vt_bf[(size_t)(b * Cch + o) * Nn + n] = (bf16)av;   // coalesced across lanes
  }
  bf16* kp = kk_bf + (size_t)idx * 64;
  #pragma unroll
  for (int j = 0; j < 8; j++)
    *(bf16x8*)(kp + j * 8) = *(const bf16x8*)&krow[j * 8];
}

// ---------------- K5: MFMA flash attention (R4 design, fixed ws layout) ------
// TM=16 queries/block, TN=128 keys/chunk. 4 waves own 32 keys each for the
// GEMMs; softmax/bias phase uses R2's per-thread layout (thread (mq,sub):
// row mq, keys sub+16j) on fp32 S staged through LDS. alpha/denominator are
// per-row (full chunk), so per-wave partial O's stay consistent.
__global__ __launch_bounds__(256) void k_attn(const bf16* __restrict__ q_bf,
                                              const bf16* __restrict__ kk_bf,
                                              const bf16* __restrict__ vt_bf,
                                              const float* __restrict__ pos,
                                              const float* __restrict__ rpe,
                                              float* __restrict__ out_dat){
  __shared__ __align__(16) bf16 ks[128][72];
  __shared__ __align__(16) bf16 vt[48][136];
  __shared__ __align__(16) float s_lds[16][132];   // fp32 logits (dot only)
  __shared__ __align__(16) bf16 ps[16][136];       // probs, bf16
  __shared__ float axs[128], wy0s[128], wy1s[128];
  __shared__ int r0s[128], r1s[128];
  __shared__ float alpha_lds[16], sfin[16];

  const int tid = threadIdx.x;
  const int b = blockIdx.x >> 8;
  const int m0 = (blockIdx.x & 255) * 16;
  const int wid = tid >> 6, lane = tid & 63;
  const int q16 = lane >> 4, l16 = lane & 15;
  const int wn0 = wid * 32;
  const int mq = tid >> 4, sub = tid & 15;   // phase-2 mapping (R2)

  // Q A-frags (persist): A[m=lane&15][k=quad*8+j]
  const bf16* qb = q_bf + ((size_t)(b * Nn + m0 + l16)) * 64;
  bf16x8 qf0 = *(const bf16x8*)(qb + q16 * 8);
  bf16x8 qf1 = *(const bf16x8*)(qb + 32 + q16 * 8);

  const float qgy = (float)(m0 >> 6) * (2.f / 63.f) - 1.f;
  const float cybase = 95.f + 47.5f * qgy;
  const float scale = 0.14433756729740643f;   // 48^-0.5
  const float bx2 = 47.5f * ((float)((m0 & 63) + mq) * (2.f / 63.f) - 1.f);

  f32x4 oacc[3];
  #pragma unroll
  for (int ct = 0; ct < 3; ct++) oacc[ct] = (f32x4){0.f, 0.f, 0.f, 0.f};
  float m_run = -1e30f, s_run = 0.f;          // per-thread: row mq (R2 style)

  for (int chk = 0; chk < 32; chk++){
    const int n0 = chk * 128;
    __syncthreads();                               // A: tiles/ps free
    // ---- stage K tile ----
    const bf16* kg = kk_bf + (size_t)(b * Nn + n0) * 64;
    #pragma unroll
    for (int j = 0; j < 4; j++){
      int f = tid + j * 256;
      int r = f >> 3, c8 = (f & 7) * 8;
      *(bf16x8*)&ks[r][c8] = *(const bf16x8*)(kg + r * 64 + c8);
    }
    // ---- stage V tile ----
    const bf16* vg = vt_bf + (size_t)b * Cch * Nn + n0;
    #pragma unroll
    for (int j = 0; j < 3; j++){
      int f = tid + j * 256;
      int r = f >> 4, c8 = (f & 15) * 8;
      *(bf16x8*)&vt[r][c8] = *(const bf16x8*)(vg + (size_t)r * Nn + c8);
    }
    // ---- per-key bias precompute ----
    if (tid < 128){
      int n = tid;
      float py = pos[(size_t)(b * Nn + n0 + n) * 2];
      float px = pos[(size_t)(b * Nn + n0 + n) * 2 + 1];
      float gyr = cybase - 47.5f * py;
      float y0f = floorf(gyr);
      float wy = gyr - y0f;
      int y0 = (int)y0f, y1 = y0 + 1;
      wy0s[n] = (y0 >= 0 && y0 < 191) ? (1.f - wy) : 0.f;
      wy1s[n] = (y1 >= 0 && y1 < 191) ? wy : 0.f;
      r0s[n] = min(max(y0, 0), 190) * 191;
      r1s[n] = min(max(y1, 0), 190) * 191;
      axs[n] = 95.f - 47.5f * px;
    }
    __syncthreads();                               // B: tiles ready
    // ---- QK^T MFMA: wave's 32 keys ----
    f32x4 s0 = (f32x4){0.f, 0.f, 0.f, 0.f};
    f32x4 s1 = (f32x4){0.f, 0.f, 0.f, 0.f};
    {
      const bf16* kr0 = &ks[wn0 + l16][q16 * 8];
      const bf16* kr1 = &ks[wn0 + 16 + l16][q16 * 8];
      bf16x8 b00 = *(const bf16x8*)kr0;
      bf16x8 b01 = *(const bf16x8*)(kr0 + 32);
      bf16x8 b10 = *(const bf16x8*)kr1;
      bf16x8 b11 = *(const bf16x8*)(kr1 + 32);
      s0 = __builtin_amdgcn_mfma_f32_16x16x32_bf16(qf0, b00, s0, 0, 0, 0);
      s0 = __builtin_amdgcn_mfma_f32_16x16x32_bf16(qf1, b01, s0, 0, 0, 0);
      s1 = __builtin_amdgcn_mfma_f32_16x16x32_bf16(qf0, b10, s1, 0, 0, 0);
      s1 = __builtin_amdgcn_mfma_f32_16x16x32_bf16(qf1, b11, s1, 0, 0, 0);
    }
    // store S to LDS per C/D map (row m = q16*4+r, col n = l16)
    #pragma unroll
    for (int r = 0; r < 4; r++){
      s_lds[q16 * 4 + r][wn0 + l16] = s0[r];
      s_lds[q16 * 4 + r][wn0 + 16 + l16] = s1[r];
    }
    __syncthreads();                               // C: S ready
    // ---- R2-style bias + online softmax: thread (mq,sub), keys sub+16j ----
    {
      float lg[8];
      float lmax = -1e30f;
      #pragma unroll
      for (int j = 0; j < 8; j++){
        int n = sub + 16 * j;
        float gxr = axs[n] + bx2;
        float x0f = floorf(gxr);
        float wx = gxr - x0f;
        int x0 = (int)x0f, x1 = x0 + 1;
        float wx0 = (x0 >= 0 && x0 < 191) ? (1.f - wx) : 0.f;
        float wx1 = (x1 >= 0 && x1 < 191) ? wx : 0.f;
        int cx0 = min(max(x0, 0), 190), cx1 = min(max(x1, 0), 190);
        int r0 = r0s[n], r1 = r1s[n];
        float bias = wy0s[n] * (wx0 * rpe[r0 + cx0] + wx1 * rpe[r0 + cx1])
                   + wy1s[n] * (wx0 * rpe[r1 + cx0] + wx1 * rpe[r1 + cx1]);
        float l = fmaf(s_lds[mq][n], scale, bias);
        lg[j] = l;
        lmax = fmaxf(lmax, l);
      }
      #pragma unroll
      for (int msk = 1; msk < 16; msk <<= 1)
        lmax = fmaxf(lmax, __shfl_xor(lmax, msk));
      float mnew = fmaxf(m_run, lmax);
      float alpha = __expf(m_run - mnew);
      m_run = mnew;
      float lsum = 0.f;
      #pragma unroll
      for (int j = 0; j < 8; j++){
        float e = __expf(lg[j] - mnew);
        lsum += e;
        ps[mq][sub + 16 * j] = (bf16)e;
      }
      #pragma unroll
      for (int msk = 1; msk < 16; msk <<= 1) lsum += __shfl_xor(lsum, msk);
      s_run = fmaf(s_run, alpha, lsum);
      if (sub == 0) alpha_lds[mq] = alpha;
    }
    __syncthreads();                               // D: P + alpha ready
    // ---- rescale partial O, PV MFMA over wave's 32 keys ----
    #pragma unroll
    for (int r = 0; r < 4; r++){
      float al = alpha_lds[q16 * 4 + r];
      oacc[0][r] *= al; oacc[1][r] *= al; oacc[2][r] *= al;
    }
    {
      bf16x8 pa = *(const bf16x8*)&ps[l16][wn0 + q16 * 8];
      #pragma unroll
      for (int ct = 0; ct < 3; ct++){
        bf16x8 vb = *(const bf16x8*)&vt[ct * 16 + l16][wn0 + q16 * 8];
        oacc[ct] = __builtin_amdgcn_mfma_f32_16x16x32_bf16(pa, vb, oacc[ct], 0, 0, 0);
      }
    }
  }
  // ---- epilogue: full-row denominators + cross-wave O reduce ----
  if (sub == 0) sfin[mq] = s_run;
  __syncthreads();
  float* ored = (float*)ks;        // [64][48] floats = 12288 B <= sizeof(ks)
  #pragma unroll
  for (int ct = 0; ct < 3; ct++)
    #pragma unroll
    for (int r = 0; r < 4; r++)
      ored[(wid * 16 + q16 * 4 + r) * 48 + ct * 16 + l16] = oacc[ct][r];
  __syncthreads();
  for (int e = 0; e < 3; e++){
    int idx = tid + e * 256;
    int m = idx / 48, c = idx % 48;
    float v = ored[m * 48 + c] + ored[(16 + m) * 48 + c]
            + ored[(32 + m) * 48 + c] + ored[(48 + m) * 48 + c];
    out_dat[(size_t)(b * Cch + c) * Nn + m0 + m] = v / sfin[m];
  }
}

// ---------------- K6: window attention (3 splits), 1 block/window ------------
__global__ __launch_bounds__(64) void k_win(const float* __restrict__ x,
                                            const float* __restrict__ iw,
                                            const float* __restrict__ ib,
                                            const float* __restrict__ bng,
                                            const float* __restrict__ bnb,
                                            const float* __restrict__ bnm,
                                            const float* __restrict__ bnv,
                                            float* __restrict__ wout){
  int s = blockIdx.x >> 7;        // split 0/1/2
  int r = blockIdx.x & 127;
  int b = r >> 6, wi = r & 63, t = threadIdx.x;
  int y, xp;
  if (s == 0){ y = (wi >> 3) * 8 + (t >> 3); xp = (wi & 7) * 8 + (t & 7); }
  else if (s == 1){ y = t; xp = wi; }      // column windows (dh=64,dw=1)
  else { y = wi; xp = t; }                  // row windows (dh=1,dw=64)
  int p = y * 64 + xp;
  __shared__ float qs[64 * 16];
  __shared__ float vs[64 * 16];
  float xrow[Cch];
  #pragma unroll
  for (int c = 0; c < Cch; c++) xrow[c] = x[(b * Cch + c) * Nn + p];
  float qrow[16];
  #pragma unroll
  for (int i = 0; i < 16; i++){
    int qc = s * 32 + i, vc = s * 32 + 16 + i;
    float aq = ib[qc], av = ib[vc];
    const float* wq_ = iw + qc * Cch;
    const float* wv_ = iw + vc * Cch;
    #pragma unroll
    for (int c = 0; c < Cch; c++){ aq += wq_[c] * xrow[c]; av += wv_[c] * xrow[c]; }
    aq = (aq - bnm[qc]) * rsqrtf(bnv[qc] + 1e-5f) * bng[qc] + bnb[qc];
    av = (av - bnm[vc]) * rsqrtf(bnv[vc] + 1e-5f) * bng[vc] + bnb[vc];
    qrow[i] = aq;
    qs[t * 16 + i] = aq;
    vs[t * 16 + i] = av;
  }
  __syncthreads();
  float l[64];
  float mx = -3.4e38f;
  #pragma unroll
  for (int j = 0; j < 64; j++){
    float d = 0.f;
    #pragma unroll
    for (int i = 0; i < 16; i++) d += qrow[i] * qs[j * 16 + i];
    l[j] = d;
    mx = fmaxf(mx, d);
  }
  float sum = 0.f;
  #pragma unroll
  for (int j = 0; j < 64; j++){ l[j] = expf(l[j] - mx); sum += l[j]; }
  float rinv = 1.f / sum;
  float o[16];
  #pragma unroll
  for (int i = 0; i < 16; i++) o[i] = 0.f;
  #pragma unroll
  for (int j = 0; j < 64; j++){
    float pj = l[j];
    #pragma unroll
    for (int i = 0; i < 16; i++) o[i] += pj * vs[j * 16 + i];
  }
  #pragma unroll
  for (int i = 0; i < 16; i++)
    wout[(b * Cch + s * 16 + i) * Nn + p] = o[i] * rinv;
}

// ---------------- K7: pout conv + 0.5/0.5 mix --------------------------------
__global__ void k_final(const float* __restrict__ win, const float* __restrict__ pw,
                        const float* __restrict__ pb, const float* __restrict__ od,
                        float* __restrict__ out){
  int chunk = blockIdx.x & 15;
  int o = (blockIdx.x >> 4) % Cch;
  int b = blockIdx.x / (16 * Cch);
  int p = chunk * 256 + threadIdx.x;
  float acc = pb[o];
  const float* ip = win + (b * Cch) * Nn + p;
  const float* wp = pw + o * Cch;
  #pragma unroll
  for (int c = 0; c < Cch; c++) acc += wp[c] * ip[c * Nn];
  out[(b * Cch + o) * Nn + p] = 0.5f * acc + 0.5f * od[(b * Cch + o) * Nn + p];
}

extern "C" void kernel_launch(void* const* d_in, const int* in_sizes, int n_in,
                              void* d_out, int out_size, void* d_ws, size_t ws_size,
                              hipStream_t stream){
  const float* x   = (const float*)d_in[0];
  const float* Wq  = (const float*)d_in[1];
  const float* bq  = (const float*)d_in[2];
  const float* dww = (const float*)d_in[3];
  const float* dwb = (const float*)d_in[4];
  const float* lng = (const float*)d_in[5];
  const float* lnb = (const float*)d_in[6];
  const float* pww = (const float*)d_in[7];
  const float* Wk  = (const float*)d_in[8];
  const float* bk  = (const float*)d_in[9];
  const float* Wv  = (const float*)d_in[10];
  const float* bv  = (const float*)d_in[11];
  const float* iw  = (const float*)d_in[12];
  const float* ib  = (const float*)d_in[13];
  const float* bng = (const float*)d_in[14];
  const float* bnb = (const float*)d_in[15];
  const float* bnm = (const float*)d_in[16];
  const float* bnv = (const float*)d_in[17];
  const float* pw  = (const float*)d_in[18];
  const float* pb  = (const float*)d_in[19];
  const float* rpe = (const float*)d_in[20];

  // Workspace layout (f32-slot offsets). NOTE: bf16 buffers need count/2 f32
  // slots — R3/R4 had q_bf sized 131072 instead of 262144, so kk_bf clobbered
  // batch 1's q_bf rows (the 5-6e-2 failures). Fixed, non-overlapping:
  float* ws    = (float*)d_ws;
  float* q     = ws;                    // [0,       393216)
  float* pos   = ws + 393216;           // [393216,  409600)
  float* xs    = ws + 409600;           // [409600,  802816)
  float* wout  = ws + 802816;           // [802816, 1196032)
  float* od    = ws + 1196032;          // [1196032,1589248)
  bf16*  q_bf  = (bf16*)(ws + 1589248); // 524288 bf16 -> [1589248,1851392)
  bf16*  kk_bf = (bf16*)(ws + 1851392); // 524288 bf16 -> [1851392,2113536)
  bf16*  vt_bf = (bf16*)(ws + 2113536); // 393216 bf16 -> [2113536,2310144)
  float* out   = (float*)d_out;         // ws total 9.24 MB (R2 used 9.5 MB OK)

  k_conv1x1   <<<Bsz * Cch * 16, 256, 0, stream>>>(x, Wq, bq, q, q_bf);
  k_offset_pos<<<(Bsz * Nn) / 64, 64, 0, stream>>>(q, dww, dwb, lng, lnb, pww, pos);
  k_sample    <<<(Bsz * Nn) / 64, 64, 0, stream>>>(x, pos, xs);
  k_kv        <<<(Bsz * Nn) / 64, 64, 0, stream>>>(xs, Wk, bk, Wv, bv, kk_bf, vt_bf);
  k_attn      <<<Bsz * 256, 256, 0, stream>>>(q_bf, kk_bf, vt_bf, pos, rpe, od);
  k_win       <<<384, 64, 0, stream>>>(x, iw, ib, bng, bnb, bnm, bnv, wout);
  k_final     <<<Bsz * Cch * 16, 256, 0, stream>>>(wout, pw, pb, od, out);
}

// Round 6
// 424.694 us; speedup vs baseline: 2.2536x; 1.1997x over previous
//
#include <hip/hip_runtime.h>
#include <hip/hip_bf16.h>
#include <math.h>

#define Bsz 2
#define Cch 48
#define Hh 64
#define Ww 64
#define Nn 4096

typedef __bf16 bf16;
typedef __attribute__((ext_vector_type(8))) __bf16 bf16x8;
typedef __attribute__((ext_vector_type(4))) float f32x4;

// ---------------- K1: conv1x1 -> q (B,C,N) fp32 + q_bf (B,m,64) bf16 --------
__global__ void k_conv1x1(const float* __restrict__ in, const float* __restrict__ Wt,
                          const float* __restrict__ bias, float* __restrict__ out,
                          bf16* __restrict__ qbf){
  int chunk = blockIdx.x & 15;            // N/256 = 16 chunks
  int o = (blockIdx.x >> 4) % Cch;
  int b = blockIdx.x / (16 * Cch);
  int p = chunk * 256 + threadIdx.x;
  float acc = bias[o];
  const float* ip = in + (b * Cch) * Nn + p;
  const float* wp = Wt + o * Cch;
  #pragma unroll
  for (int c = 0; c < Cch; c++) acc += wp[c] * ip[c * Nn];
  out[(b * Cch + o) * Nn + p] = acc;
  size_t qb = ((size_t)(b * Nn + p)) * 64;
  qbf[qb + o] = (bf16)acc;
  if (o < 16) qbf[qb + 48 + o] = (bf16)0.f;   // zero-pad k=48..63
}

// ---------------- K2: dw3x3 + LN + GELU + pw(2) + tanh -> pos ----------------
__global__ void k_offset_pos(const float* __restrict__ q, const float* __restrict__ dww,
                             const float* __restrict__ dwb, const float* __restrict__ lng,
                             const float* __restrict__ lnb, const float* __restrict__ pww,
                             float* __restrict__ pos){
  int idx = blockIdx.x * 64 + threadIdx.x;
  if (idx >= Bsz * Nn) return;
  int b = idx >> 12;
  int p = idx & (Nn - 1);
  int y = p >> 6, x = p & 63;
  float t[Cch];
  float mean = 0.f;
  #pragma unroll
  for (int c = 0; c < Cch; c++){
    float acc = dwb[c];
    const float* qc = q + (b * Cch + c) * Nn;
    #pragma unroll
    for (int ky = -1; ky <= 1; ky++){
      int yy = y + ky;
      if (yy < 0 || yy >= Hh) continue;
      #pragma unroll
      for (int kx = -1; kx <= 1; kx++){
        int xx = x + kx;
        if (xx < 0 || xx >= Ww) continue;
        acc += qc[yy * Ww + xx] * dww[c * 9 + (ky + 1) * 3 + (kx + 1)];
      }
    }
    t[c] = acc; mean += acc;
  }
  mean *= (1.f / Cch);
  float var = 0.f;
  #pragma unroll
  for (int c = 0; c < Cch; c++){ float d = t[c] - mean; var += d * d; }
  var *= (1.f / Cch);
  float rstd = rsqrtf(var + 1e-5f);
  float o0 = 0.f, o1 = 0.f;
  #pragma unroll
  for (int c = 0; c < Cch; c++){
    float u = (t[c] - mean) * rstd * lng[c] + lnb[c];
    u = 0.5f * u * (1.f + erff(u * 0.70710678118654752f));   // exact gelu
    o0 += pww[c] * u;
    o1 += pww[Cch + c] * u;
  }
  float posy = tanhf(o0) * (2.f / 63.f) + ((0.5f + (float)y) * (2.f / 63.f) - 1.f);
  float posx = tanhf(o1) * (2.f / 63.f) + ((0.5f + (float)x) * (2.f / 63.f) - 1.f);
  pos[idx * 2 + 0] = posy;
  pos[idx * 2 + 1] = posx;
}

// ---------------- K3: fused bilinear sample + k,v projection -----------------
// row stays in registers (saves the xs round-trip + one launch).
__global__ void k_samplekv(const float* __restrict__ x, const float* __restrict__ pos,
                           const float* __restrict__ Wk, const float* __restrict__ bk,
                           const float* __restrict__ Wv, const float* __restrict__ bv,
                           bf16* __restrict__ kk_bf, bf16* __restrict__ vt_bf){
  int idx = blockIdx.x * 64 + threadIdx.x;
  if (idx >= Bsz * Nn) return;
  int b = idx >> 12;
  int n = idx & (Nn - 1);
  float py = pos[idx * 2], px = pos[idx * 2 + 1];
  float gx = (px + 1.f) * 0.5f * 63.f;
  float gy = (py + 1.f) * 0.5f * 63.f;
  float x0f = floorf(gx), y0f = floorf(gy);
  float wx = gx - x0f, wy = gy - y0f;
  int x0 = (int)x0f, y0 = (int)y0f, x1 = x0 + 1, y1 = y0 + 1;
  float w00 = (1.f - wy) * (1.f - wx), w01 = (1.f - wy) * wx;
  float w10 = wy * (1.f - wx),         w11 = wy * wx;
  bool vx0 = (x0 >= 0) && (x0 < Ww), vx1 = (x1 >= 0) && (x1 < Ww);
  bool vy0 = (y0 >= 0) && (y0 < Hh), vy1 = (y1 >= 0) && (y1 < Hh);
  if (!(vx0 && vy0)) w00 = 0.f;
  if (!(vx1 && vy0)) w01 = 0.f;
  if (!(vx0 && vy1)) w10 = 0.f;
  if (!(vx1 && vy1)) w11 = 0.f;
  int cx0 = min(max(x0, 0), Ww - 1), cx1 = min(max(x1, 0), Ww - 1);
  int cy0 = min(max(y0, 0), Hh - 1), cy1 = min(max(y1, 0), Hh - 1);
  int i00 = cy0 * Ww + cx0, i01 = cy0 * Ww + cx1;
  int i10 = cy1 * Ww + cx0, i11 = cy1 * Ww + cx1;
  const float* xb = x + (b * Cch) * Nn;
  float row[Cch];
  #pragma unroll
  for (int c = 0; c < Cch; c++){
    const float* xc = xb + c * Nn;
    row[c] = w00 * xc[i00] + w01 * xc[i01] + w10 * xc[i10] + w11 * xc[i11];
  }
  __align__(16) bf16 krow[64];
  #pragma unroll
  for (int j = 48; j < 64; j++) krow[j] = (bf16)0.f;
  for (int o = 0; o < Cch; o++){
    float ak = bk[o], av = bv[o];
    const float* wkr = Wk + o * Cch;
    const float* wvr = Wv + o * Cch;
    #pragma unroll
    for (int c = 0; c < Cch; c++){ ak += wkr[c] * row[c]; av += wvr[c] * row[c]; }
    krow[o] = (bf16)ak;
    vt_bf[(size_t)(b * Cch + o) * Nn + n] = (bf16)av;   // coalesced across lanes
  }
  bf16* kp = kk_bf + (size_t)idx * 64;
  #pragma unroll
  for (int j = 0; j < 8; j++)
    *(bf16x8*)(kp + j * 8) = *(const bf16x8*)&krow[j * 8];
}

// ---------------- K4: MFMA flash attention, split-K=2 ------------------------
// TM=16 queries/block, keys [kp*2048,(kp+1)*2048) in 16 chunks of 128.
// 4 waves own 32 keys each. Bias applied in C-layout registers (no fp32 S
// round-trip). Cross-wave row-max via wmax2 (identical mnew/alpha in all
// waves); per-wave partial O and denominator, merged in epilogue; split-K
// halves merged by k_merge (log-sum-exp). 3 barriers/chunk, LDS 38.7KB ->
// 4 blocks/CU.
__global__ __launch_bounds__(256) void k_attn(const bf16* __restrict__ q_bf,
                                              const bf16* __restrict__ kk_bf,
                                              const bf16* __restrict__ vt_bf,
                                              const float* __restrict__ pos,
                                              const float* __restrict__ rpe,
                                              float* __restrict__ o_part,
                                              float* __restrict__ s_part,
                                              float* __restrict__ m_part){
  __shared__ __align__(16) bf16 ks[128][72];
  __shared__ __align__(16) bf16 vt[48][136];
  __shared__ __align__(16) bf16 ps[16][136];
  __shared__ float axs[128], wy0s[128], wy1s[128];
  __shared__ int r0s[128], r1s[128];
  __shared__ __align__(16) float wmax2[16][4];

  const int tid = threadIdx.x;
  const int b  = blockIdx.x >> 9;
  const int kp = (blockIdx.x >> 8) & 1;
  const int m0 = (blockIdx.x & 255) * 16;
  const int wid = tid >> 6, lane = tid & 63;
  const int q16 = lane >> 4, l16 = lane & 15;
  const int wn0 = wid * 32;

  // Q A-frags (persist): A[m=lane&15][k=quad*8+j]
  const bf16* qb = q_bf + ((size_t)(b * Nn + m0 + l16)) * 64;
  bf16x8 qf0 = *(const bf16x8*)(qb + q16 * 8);
  bf16x8 qf1 = *(const bf16x8*)(qb + 32 + q16 * 8);

  const float qgy = (float)(m0 >> 6) * (2.f / 63.f) - 1.f;
  const float cybase = 95.f + 47.5f * qgy;
  const float scale = 0.14433756729740643f;   // 48^-0.5
  float bxr[4];
  #pragma unroll
  for (int r = 0; r < 4; r++){
    int mcol = (m0 & 63) + q16 * 4 + r;       // query for S-row q16*4+r
    bxr[r] = 47.5f * ((float)mcol * (2.f / 63.f) - 1.f);
  }

  f32x4 oacc[3];
  #pragma unroll
  for (int ct = 0; ct < 3; ct++) oacc[ct] = (f32x4){0.f, 0.f, 0.f, 0.f};
  float m_run[4] = {-1e30f, -1e30f, -1e30f, -1e30f};   // identical across waves
  float s_runw[4] = {0.f, 0.f, 0.f, 0.f};              // wave-partial denom

  for (int chk = 0; chk < 16; chk++){
    const int n0 = kp * 2048 + chk * 128;
    __syncthreads();                               // A: tiles/ps free
    // ---- stage K tile ----
    const bf16* kg = kk_bf + (size_t)(b * Nn + n0) * 64;
    #pragma unroll
    for (int j = 0; j < 4; j++){
      int f = tid + j * 256;
      int r = f >> 3, c8 = (f & 7) * 8;
      *(bf16x8*)&ks[r][c8] = *(const bf16x8*)(kg + r * 64 + c8);
    }
    // ---- stage V tile ----
    const bf16* vg = vt_bf + (size_t)b * Cch * Nn + n0;
    #pragma unroll
    for (int j = 0; j < 3; j++){
      int f = tid + j * 256;
      int r = f >> 4, c8 = (f & 15) * 8;
      *(bf16x8*)&vt[r][c8] = *(const bf16x8*)(vg + (size_t)r * Nn + c8);
    }
    // ---- per-key bias precompute ----
    if (tid < 128){
      int n = tid;
      float py = pos[(size_t)(b * Nn + n0 + n) * 2];
      float px = pos[(size_t)(b * Nn + n0 + n) * 2 + 1];
      float gyr = cybase - 47.5f * py;
      float y0f = floorf(gyr);
      float wy = gyr - y0f;
      int y0 = (int)y0f, y1 = y0 + 1;
      wy0s[n] = (y0 >= 0 && y0 < 191) ? (1.f - wy) : 0.f;
      wy1s[n] = (y1 >= 0 && y1 < 191) ? wy : 0.f;
      r0s[n] = min(max(y0, 0), 190) * 191;
      r1s[n] = min(max(y1, 0), 190) * 191;
      axs[n] = 95.f - 47.5f * px;
    }
    __syncthreads();                               // B: tiles ready
    // ---- QK^T MFMA: wave's 32 keys ----
    f32x4 s0 = (f32x4){0.f, 0.f, 0.f, 0.f};
    f32x4 s1 = (f32x4){0.f, 0.f, 0.f, 0.f};
    {
      const bf16* kr0 = &ks[wn0 + l16][q16 * 8];
      const bf16* kr1 = &ks[wn0 + 16 + l16][q16 * 8];
      bf16x8 b00 = *(const bf16x8*)kr0;
      bf16x8 b01 = *(const bf16x8*)(kr0 + 32);
      bf16x8 b10 = *(const bf16x8*)kr1;
      bf16x8 b11 = *(const bf16x8*)(kr1 + 32);
      s0 = __builtin_amdgcn_mfma_f32_16x16x32_bf16(qf0, b00, s0, 0, 0, 0);
      s0 = __builtin_amdgcn_mfma_f32_16x16x32_bf16(qf1, b01, s0, 0, 0, 0);
      s1 = __builtin_amdgcn_mfma_f32_16x16x32_bf16(qf0, b10, s1, 0, 0, 0);
      s1 = __builtin_amdgcn_mfma_f32_16x16x32_bf16(qf1, b11, s1, 0, 0, 0);
    }
    // ---- bias + scale in C-layout regs (row m = q16*4+r, col n-tile = l16) --
    float sl[2][4];
    #pragma unroll
    for (int r = 0; r < 4; r++){ sl[0][r] = s0[r]; sl[1][r] = s1[r]; }
    float rowmax[4] = {-1e30f, -1e30f, -1e30f, -1e30f};
    #pragma unroll
    for (int nt = 0; nt < 2; nt++){
      int nl = wn0 + nt * 16 + l16;
      float ax = axs[nl], wy0 = wy0s[nl], wy1 = wy1s[nl];
      int r0 = r0s[nl], r1 = r1s[nl];
      #pragma unroll
      for (int r = 0; r < 4; r++){
        float gxr = ax + bxr[r];
        float x0f = floorf(gxr);
        float wx = gxr - x0f;
        int x0 = (int)x0f, x1 = x0 + 1;
        float wx0 = (x0 >= 0 && x0 < 191) ? (1.f - wx) : 0.f;
        float wx1 = (x1 >= 0 && x1 < 191) ? wx : 0.f;
        int cx0 = min(max(x0, 0), 190), cx1 = min(max(x1, 0), 190);
        float bias = wy0 * (wx0 * rpe[r0 + cx0] + wx1 * rpe[r0 + cx1])
                   + wy1 * (wx0 * rpe[r1 + cx0] + wx1 * rpe[r1 + cx1]);
        float lg = fmaf(sl[nt][r], scale, bias);
        sl[nt][r] = lg;
        rowmax[r] = fmaxf(rowmax[r], lg);
      }
    }
    #pragma unroll
    for (int r = 0; r < 4; r++){
      #pragma unroll
      for (int msk = 1; msk < 16; msk <<= 1)
        rowmax[r] = fmaxf(rowmax[r], __shfl_xor(rowmax[r], msk));
    }
    if (l16 == 0){
      #pragma unroll
      for (int r = 0; r < 4; r++) wmax2[q16 * 4 + r][wid] = rowmax[r];
    }
    __syncthreads();                               // C: wmax ready
    #pragma unroll
    for (int r = 0; r < 4; r++){
      f32x4 wv = *(const f32x4*)&wmax2[q16 * 4 + r][0];
      float cmax = fmaxf(fmaxf(wv[0], wv[1]), fmaxf(wv[2], wv[3]));
      float mnew = fmaxf(m_run[r], cmax);          // identical in all waves
      float alpha = __expf(m_run[r] - mnew);
      m_run[r] = mnew;
      sl[0][r] = __expf(sl[0][r] - mnew);
      sl[1][r] = __expf(sl[1][r] - mnew);
      float rs = sl[0][r] + sl[1][r];
      #pragma unroll
      for (int msk = 1; msk < 16; msk <<= 1) rs += __shfl_xor(rs, msk);
      s_runw[r] = fmaf(s_runw[r], alpha, rs);
      #pragma unroll
      for (int ct = 0; ct < 3; ct++) oacc[ct][r] *= alpha;
      ps[q16 * 4 + r][wn0 + l16] = (bf16)sl[0][r];
      ps[q16 * 4 + r][wn0 + 16 + l16] = (bf16)sl[1][r];
    }
    // ---- PV MFMA: wave's own 32 P-columns (same-wave LDS, no barrier) ------
    {
      bf16x8 pa = *(const bf16x8*)&ps[l16][wn0 + q16 * 8];
      #pragma unroll
      for (int ct = 0; ct < 3; ct++){
        bf16x8 vb = *(const bf16x8*)&vt[ct * 16 + l16][wn0 + q16 * 8];
        oacc[ct] = __builtin_amdgcn_mfma_f32_16x16x32_bf16(pa, vb, oacc[ct], 0, 0, 0);
      }
    }
  }
  // ---- epilogue: cross-wave reduce -> o_part[b][kp][c][m], s_part, m_part ---
  __syncthreads();
  float* ored = (float*)ks;        // [4][16][48] f32 = 12288 B
  float* sred = (float*)vt;        // [4][16]
  #pragma unroll
  for (int ct = 0; ct < 3; ct++)
    #pragma unroll
    for (int r = 0; r < 4; r++)
      ored[(wid * 16 + q16 * 4 + r) * 48 + ct * 16 + l16] = oacc[ct][r];
  if (l16 == 0){
    #pragma unroll
    for (int r = 0; r < 4; r++) sred[wid * 16 + q16 * 4 + r] = s_runw[r];
  }
  __syncthreads();
  size_t obase = ((size_t)(b * 2 + kp) * Cch) * Nn;
  #pragma unroll
  for (int e = 0; e < 3; e++){
    int idx = tid + e * 256;         // 768 = 48c x 16m
    int c = idx >> 4, mm = idx & 15;
    float v = ored[mm * 48 + c] + ored[(16 + mm) * 48 + c]
            + ored[(32 + mm) * 48 + c] + ored[(48 + mm) * 48 + c];
    o_part[obase + (size_t)c * Nn + m0 + mm] = v;    // coalesced in mm
  }
  if (tid < 16)
    s_part[(size_t)(b * 2 + kp) * Nn + m0 + tid] =
        sred[tid] + sred[16 + tid] + sred[32 + tid] + sred[48 + tid];
  if (wid == 0 && l16 == 0){
    #pragma unroll
    for (int r = 0; r < 4; r++)
      m_part[(size_t)(b * 2 + kp) * Nn + m0 + q16 * 4 + r] = m_run[r];
  }
}

// ---------------- K5: split-K merge (log-sum-exp combine) --------------------
__global__ void k_merge(const float* __restrict__ o_part, const float* __restrict__ s_part,
                        const float* __restrict__ m_part, float* __restrict__ od){
  int idx = blockIdx.x * 256 + threadIdx.x;   // (b, m)
  int b = idx >> 12, m = idx & (Nn - 1);
  float ma = m_part[(size_t)(b * 2) * Nn + m];
  float mb = m_part[(size_t)(b * 2 + 1) * Nn + m];
  float mm = fmaxf(ma, mb);
  float e0 = __expf(ma - mm), e1 = __expf(mb - mm);
  float s = s_part[(size_t)(b * 2) * Nn + m] * e0
          + s_part[(size_t)(b * 2 + 1) * Nn + m] * e1;
  float rinv = 1.f / s;
  e0 *= rinv; e1 *= rinv;
  const float* o0 = o_part + (size_t)(b * 2) * Cch * Nn + m;
  const float* o1 = o_part + (size_t)(b * 2 + 1) * Cch * Nn + m;
  float* op = od + (size_t)b * Cch * Nn + m;
  #pragma unroll
  for (int c = 0; c < Cch; c++)
    op[(size_t)c * Nn] = o0[(size_t)c * Nn] * e0 + o1[(size_t)c * Nn] * e1;
}

// ---------------- K6: window attention (3 splits), 1 block/window ------------
__global__ __launch_bounds__(64) void k_win(const float* __restrict__ x,
                                            const float* __restrict__ iw,
                                            const float* __restrict__ ib,
                                            const float* __restrict__ bng,
                                            const float* __restrict__ bnb,
                                            const float* __restrict__ bnm,
                                            const float* __restrict__ bnv,
                                            float* __restrict__ wout){
  int s = blockIdx.x >> 7;        // split 0/1/2
  int r = blockIdx.x & 127;
  int b = r >> 6, wi = r & 63, t = threadIdx.x;
  int y, xp;
  if (s == 0){ y = (wi >> 3) * 8 + (t >> 3); xp = (wi & 7) * 8 + (t & 7); }
  else if (s == 1){ y = t; xp = wi; }      // column windows (dh=64,dw=1)
  else { y = wi; xp = t; }                  // row windows (dh=1,dw=64)
  int p = y * 64 + xp;
  __shared__ float qs[64 * 16];
  __shared__ float vs[64 * 16];
  float xrow[Cch];
  #pragma unroll
  for (int c = 0; c < Cch; c++) xrow[c] = x[(b * Cch + c) * Nn + p];
  float qrow[16];
  #pragma unroll
  for (int i = 0; i < 16; i++){
    int qc = s * 32 + i, vc = s * 32 + 16 + i;
    float aq = ib[qc], av = ib[vc];
    const float* wq_ = iw + qc * Cch;
    const float* wv_ = iw + vc * Cch;
    #pragma unroll
    for (int c = 0; c < Cch; c++){ aq += wq_[c] * xrow[c]; av += wv_[c] * xrow[c]; }
    aq = (aq - bnm[qc]) * rsqrtf(bnv[qc] + 1e-5f) * bng[qc] + bnb[qc];
    av = (av - bnm[vc]) * rsqrtf(bnv[vc] + 1e-5f) * bng[vc] + bnb[vc];
    qrow[i] = aq;
    qs[t * 16 + i] = aq;
    vs[t * 16 + i] = av;
  }
  __syncthreads();
  float l[64];
  float mx = -3.4e38f;
  #pragma unroll
  for (int j = 0; j < 64; j++){
    float d = 0.f;
    #pragma unroll
    for (int i = 0; i < 16; i++) d += qrow[i] * qs[j * 16 + i];
    l[j] = d;
    mx = fmaxf(mx, d);
  }
  float sum = 0.f;
  #pragma unroll
  for (int j = 0; j < 64; j++){ l[j] = expf(l[j] - mx); sum += l[j]; }
  float rinv = 1.f / sum;
  float o[16];
  #pragma unroll
  for (int i = 0; i < 16; i++) o[i] = 0.f;
  #pragma unroll
  for (int j = 0; j < 64; j++){
    float pj = l[j];
    #pragma unroll
    for (int i = 0; i < 16; i++) o[i] += pj * vs[j * 16 + i];
  }
  #pragma unroll
  for (int i = 0; i < 16; i++)
    wout[(b * Cch + s * 16 + i) * Nn + p] = o[i] * rinv;
}

// ---------------- K7: pout conv + 0.5/0.5 mix --------------------------------
__global__ void k_final(const float* __restrict__ win, const float* __restrict__ pw,
                        const float* __restrict__ pb, const float* __restrict__ od,
                        float* __restrict__ out){
  int chunk = blockIdx.x & 15;
  int o = (blockIdx.x >> 4) % Cch;
  int b = blockIdx.x / (16 * Cch);
  int p = chunk * 256 + threadIdx.x;
  float acc = pb[o];
  const float* ip = win + (b * Cch) * Nn + p;
  const float* wp = pw + o * Cch;
  #pragma unroll
  for (int c = 0; c < Cch; c++) acc += wp[c] * ip[c * Nn];
  out[(b * Cch + o) * Nn + p] = 0.5f * acc + 0.5f * od[(b * Cch + o) * Nn + p];
}

extern "C" void kernel_launch(void* const* d_in, const int* in_sizes, int n_in,
                              void* d_out, int out_size, void* d_ws, size_t ws_size,
                              hipStream_t stream){
  const float* x   = (const float*)d_in[0];
  const float* Wq  = (const float*)d_in[1];
  const float* bq  = (const float*)d_in[2];
  const float* dww = (const float*)d_in[3];
  const float* dwb = (const float*)d_in[4];
  const float* lng = (const float*)d_in[5];
  const float* lnb = (const float*)d_in[6];
  const float* pww = (const float*)d_in[7];
  const float* Wk  = (const float*)d_in[8];
  const float* bk  = (const float*)d_in[9];
  const float* Wv  = (const float*)d_in[10];
  const float* bv  = (const float*)d_in[11];
  const float* iw  = (const float*)d_in[12];
  const float* ib  = (const float*)d_in[13];
  const float* bng = (const float*)d_in[14];
  const float* bnb = (const float*)d_in[15];
  const float* bnm = (const float*)d_in[16];
  const float* bnv = (const float*)d_in[17];
  const float* pw  = (const float*)d_in[18];
  const float* pb  = (const float*)d_in[19];
  const float* rpe = (const float*)d_in[20];

  // Workspace (f32-slot offsets). o_part REUSES [0,786432): q (read only by
  // k_offset_pos) and the former xs slot — both dead before k_attn runs.
  float* ws     = (float*)d_ws;
  float* q      = ws;                    // [0,       393216)  dead after K2
  float* o_part = ws;                    // [0,       786432)  written by k_attn
  float* pos    = ws + 786432;           // [786432,  802816)
  float* wout   = ws + 802816;           // [802816, 1196032)
  float* od     = ws + 1196032;          // [1196032,1589248)
  bf16*  q_bf   = (bf16*)(ws + 1589248); // 524288 bf16 -> [1589248,1851392)
  bf16*  kk_bf  = (bf16*)(ws + 1851392); // 524288 bf16 -> [1851392,2113536)
  bf16*  vt_bf  = (bf16*)(ws + 2113536); // 393216 bf16 -> [2113536,2310144)
  float* s_part = ws + 2310144;          // [2310144,2326528)
  float* m_part = ws + 2326528;          // [2326528,2342912) = 9.37 MB total
  float* out    = (float*)d_out;

  k_conv1x1   <<<Bsz * Cch * 16, 256, 0, stream>>>(x, Wq, bq, q, q_bf);
  k_offset_pos<<<(Bsz * Nn) / 64, 64, 0, stream>>>(q, dww, dwb, lng, lnb, pww, pos);
  k_samplekv  <<<(Bsz * Nn) / 64, 64, 0, stream>>>(x, pos, Wk, bk, Wv, bv, kk_bf, vt_bf);
  k_attn      <<<Bsz * 512, 256, 0, stream>>>(q_bf, kk_bf, vt_bf, pos, rpe,
                                              o_part, s_part, m_part);
  k_merge     <<<(Bsz * Nn) / 256, 256, 0, stream>>>(o_part, s_part, m_part, od);
  k_win       <<<384, 64, 0, stream>>>(x, iw, ib, bng, bnb, bnm, bnv, wout);
  k_final     <<<Bsz * Cch * 16, 256, 0, stream>>>(wout, pw, pb, od, out);
}